// Round 3
// baseline (498.221 us; speedup 1.0000x reference)
//
#include <hip/hip_runtime.h>
#include <stdint.h>
#include <stddef.h>

#define HN   12
#define SN   2048
#define EN   768
#define DKN  64
#define BATCH 4
#define MROWS 8192   // BATCH*SN

typedef short bf16x8 __attribute__((ext_vector_type(8)));
typedef float f32x4 __attribute__((ext_vector_type(4)));

__device__ __forceinline__ unsigned short f2bf(float f) {
  union { float f; unsigned u; } x; x.f = f;
  unsigned r = x.u + 0x7fffu + ((x.u >> 16) & 1u);
  return (unsigned short)(r >> 16);
}

#if __has_builtin(__builtin_amdgcn_cvt_pk_bf16_f32)
typedef __bf16 bf16v2 __attribute__((ext_vector_type(2)));
__device__ __forceinline__ unsigned pk_bf16(float a, float b) {
  union { bf16v2 v; unsigned u; } c;
  c.v = __builtin_amdgcn_cvt_pk_bf16_f32(a, b);
  return c.u;
}
#else
__device__ __forceinline__ unsigned pk_bf16(float a, float b) {
  return (unsigned)f2bf(a) | ((unsigned)f2bf(b) << 16);
}
#endif

// byte-pair expand: from byte-mask word m (bytes m3 m2 m1 m0), build [m1 m1 m0 m0] / [m3 m3 m2 m2]
#if __has_builtin(__builtin_amdgcn_perm)
__device__ __forceinline__ unsigned pmexp(unsigned m, unsigned sel) {
  return __builtin_amdgcn_perm(m, m, sel);
}
#else
__device__ __forceinline__ unsigned pmexp(unsigned m, unsigned sel) {
  const unsigned b0 = (m >> (8 * (sel & 3))) & 0xFFu;
  const unsigned b1 = (m >> (8 * ((sel >> 16) & 3))) & 0xFFu;
  return (b0 ? 0xFFFFu : 0u) | (b1 ? 0xFFFF0000u : 0u);
}
#endif

#define GLD_LDS16(gptr, lptr) \
  __builtin_amdgcn_global_load_lds((const __attribute__((address_space(1))) void*)(gptr), \
                                   (__attribute__((address_space(3))) void*)(lptr), 16, 0, 0)

// ---------------------------------------------------------------- fused f32 -> bf16
#define NBIG4 1572864   // NBIG/4
#define NW4   147456    // NW/4
__global__ __launch_bounds__(256) void cvt_all(const float* __restrict__ q,
                                               const float* __restrict__ k,
                                               const float* __restrict__ v,
                                               const float* __restrict__ wq,
                                               const float* __restrict__ wk,
                                               const float* __restrict__ wv,
                                               const float* __restrict__ wo,
                                               unsigned short* __restrict__ dst) {
  const int i = blockIdx.x * 256 + threadIdx.x;
  const float* src;
  int off;
  if (i < 3 * NBIG4) {
    const int r = i / NBIG4;
    src = (r == 0) ? q : (r == 1) ? k : v;
    off = i - r * NBIG4;
  } else {
    const int j = i - 3 * NBIG4;
    const int r = j / NW4;
    src = (r == 0) ? wq : (r == 1) ? wk : (r == 2) ? wv : wo;
    off = j - r * NW4;
  }
  float4 val = ((const float4*)src)[off];
  ushort4 o;
  o.x = f2bf(val.x); o.y = f2bf(val.y); o.z = f2bf(val.z); o.w = f2bf(val.w);
  ((ushort4*)dst)[i] = o;
}

// ---------------------------------------------------------------- mask -> keep-byte table
// keep = (mask==0) -> 0xFF ; exclude -> 0x00.  out u32 packs 4 consecutive keys.
__global__ __launch_bounds__(256) void mask_bytes(const int* __restrict__ mask,
                                                  unsigned* __restrict__ out) {
  const size_t i = (size_t)blockIdx.x * 256 + threadIdx.x;
  const int4 v = ((const int4*)mask)[i];
  unsigned o = (v.x ? 0u : 0xFFu) | (v.y ? 0u : 0xFF00u) |
               (v.z ? 0u : 0xFF0000u) | (v.w ? 0u : 0xFF000000u);
  out[i] = o;
}

// ---------------------------------------------------------------- batched QKV GEMM
// z=0: Q (scaled, [B,H,S,DK]); z=1: K ([B,H,S,DK]); z=2: V transposed ([B,H,DK,S])
__global__ __launch_bounds__(256) void gemm_qkv(const unsigned short* __restrict__ Xb,
                                                const unsigned short* __restrict__ Wb,
                                                unsigned short* __restrict__ Ob,
                                                float qscale) {
  __shared__ unsigned short As[128 * 32];
  __shared__ unsigned short Bs[128 * 32];
  const int tid  = threadIdx.x;
  const int wave = tid >> 6;
  const int lane = tid & 63;
  const int quad = lane >> 4;
  const int l16  = lane & 15;
  const int bm = blockIdx.x;
  const int bn = blockIdx.y;
  const int z  = blockIdx.z;
  const int wm = wave & 1;
  const int wn = wave >> 1;

  const unsigned short* X = Xb + (size_t)z * MROWS * EN;
  const unsigned short* W = Wb + (size_t)z * EN * EN;
  unsigned short* O = Ob + (size_t)z * MROWS * EN;

  f32x4 acc[4][4] = {};
  const int srow = lane >> 2;
  const int schk = lane & 3;

  for (int bk = 0; bk < 24; ++bk) {
    __syncthreads();
#pragma unroll
    for (int r = 0; r < 2; ++r) {
      const int rowblk = r * 64 + wave * 16;
      GLD_LDS16(X + (size_t)(bm * 128 + rowblk + srow) * EN + bk * 32 + schk * 8,
                As + rowblk * 32);
      GLD_LDS16(W + (size_t)(bn * 128 + rowblk + srow) * EN + bk * 32 + schk * 8,
                Bs + rowblk * 32);
    }
    __syncthreads();

    bf16x8 af[4], bfr[4];
#pragma unroll
    for (int mt = 0; mt < 4; ++mt)
      af[mt] = *(const bf16x8*)&As[(wm * 64 + mt * 16 + l16) * 32 + quad * 8];
#pragma unroll
    for (int nt = 0; nt < 4; ++nt)
      bfr[nt] = *(const bf16x8*)&Bs[(wn * 64 + nt * 16 + l16) * 32 + quad * 8];
#pragma unroll
    for (int mt = 0; mt < 4; ++mt)
#pragma unroll
      for (int nt = 0; nt < 4; ++nt)
        acc[mt][nt] = __builtin_amdgcn_mfma_f32_16x16x32_bf16(af[mt], bfr[nt], acc[mt][nt], 0, 0, 0);
  }

  const int m0 = bm * 128 + wm * 64;
  const int n0 = bn * 128 + wn * 64;
  const float scale = (z == 0) ? qscale : 1.0f;

  if (z < 2) {
#pragma unroll
    for (int mt = 0; mt < 4; ++mt) {
#pragma unroll
      for (int nt = 0; nt < 4; ++nt) {
        const int n = n0 + nt * 16 + l16;
        const int h = n >> 6, d = n & 63;
#pragma unroll
        for (int r = 0; r < 4; ++r) {
          const int m = m0 + mt * 16 + quad * 4 + r;
          const int b = m >> 11, s = m & 2047;
          O[((size_t)(b * HN + h) * SN + s) * DKN + d] = f2bf(acc[mt][nt][r] * scale);
        }
      }
    }
  } else {
#pragma unroll
    for (int mt = 0; mt < 4; ++mt) {
#pragma unroll
      for (int nt = 0; nt < 4; ++nt) {
        const int n = n0 + nt * 16 + l16;
        const int h = n >> 6, d = n & 63;
        const int m = m0 + mt * 16 + quad * 4;
        const int b = m >> 11, s = m & 2047;
        ushort4 pk;
        pk.x = f2bf(acc[mt][nt][0]);
        pk.y = f2bf(acc[mt][nt][1]);
        pk.z = f2bf(acc[mt][nt][2]);
        pk.w = f2bf(acc[mt][nt][3]);
        *(ushort4*)&O[((size_t)(b * HN + h) * DKN + d) * SN + s] = pk;
      }
    }
  }
}

// ---------------------------------------------------------------- GEMM  C = X @ W^T + residual (f32 out)
__global__ __launch_bounds__(256) void gemm_out(const unsigned short* __restrict__ X,
                                                const unsigned short* __restrict__ W,
                                                float* __restrict__ O,
                                                const float* __restrict__ residual) {
  __shared__ unsigned short As[128 * 32];
  __shared__ unsigned short Bs[128 * 32];
  const int tid  = threadIdx.x;
  const int wave = tid >> 6;
  const int lane = tid & 63;
  const int quad = lane >> 4;
  const int l16  = lane & 15;
  const int bm = blockIdx.x;
  const int bn = blockIdx.y;
  const int wm = wave & 1;
  const int wn = wave >> 1;

  f32x4 acc[4][4] = {};
  const int srow = lane >> 2;
  const int schk = lane & 3;

  for (int bk = 0; bk < 24; ++bk) {
    __syncthreads();
#pragma unroll
    for (int r = 0; r < 2; ++r) {
      const int rowblk = r * 64 + wave * 16;
      GLD_LDS16(X + (size_t)(bm * 128 + rowblk + srow) * EN + bk * 32 + schk * 8,
                As + rowblk * 32);
      GLD_LDS16(W + (size_t)(bn * 128 + rowblk + srow) * EN + bk * 32 + schk * 8,
                Bs + rowblk * 32);
    }
    __syncthreads();

    bf16x8 af[4], bfr[4];
#pragma unroll
    for (int mt = 0; mt < 4; ++mt)
      af[mt] = *(const bf16x8*)&As[(wm * 64 + mt * 16 + l16) * 32 + quad * 8];
#pragma unroll
    for (int nt = 0; nt < 4; ++nt)
      bfr[nt] = *(const bf16x8*)&Bs[(wn * 64 + nt * 16 + l16) * 32 + quad * 8];
#pragma unroll
    for (int mt = 0; mt < 4; ++mt)
#pragma unroll
      for (int nt = 0; nt < 4; ++nt)
        acc[mt][nt] = __builtin_amdgcn_mfma_f32_16x16x32_bf16(af[mt], bfr[nt], acc[mt][nt], 0, 0, 0);
  }

  const int m0 = bm * 128 + wm * 64;
  const int n0 = bn * 128 + wn * 64;
#pragma unroll
  for (int mt = 0; mt < 4; ++mt) {
#pragma unroll
    for (int nt = 0; nt < 4; ++nt) {
      const int n = n0 + nt * 16 + l16;
#pragma unroll
      for (int r = 0; r < 4; ++r) {
        const int m = m0 + mt * 16 + quad * 4 + r;
        const size_t idx = (size_t)m * EN + n;
        O[idx] = acc[mt][nt][r] + residual[idx];
      }
    }
  }
}

// ---------------------------------------------------------------- flash attention (key-split waves)
// Wave = (qhalf, keyhalf): 32q x 32k. O additive over keys -> combine halves once at end.
// Q pre-scaled by 0.125*log2e (bare exp2 softmax, uniform bias cancels in O/l).
// ROUND 3: registers-only kt loop.
//  - K/V fragments loaded straight from global (L2-resident; staging permutation folded
//    into the per-lane global address — correctness proven in round 1).
//  - ONE-TILE prefetch distance (T14): LD_K(kt+1) issues right after QK^T consumes ak,
//    LD_M/LD_V(kt+1) after softmax/PV consume them. WAR on the same registers pins
//    issue order; compiler's counted vmcnt gives each load a full phase of cover.
//  - Mask via precomputed keep-byte table: 2x 8B load + 4 v_perm + 4 v_and per kt
//    replaces 48 shift/ashr/and ops.
//  - No barriers / no LDS in the loop (LDS only for the final half-combine).
//  - (kt+1)&31 wraps the last prefetch in-bounds.
__global__ __launch_bounds__(256, 4) void attn_kernel(const unsigned short* __restrict__ Q,
                                                      const unsigned short* __restrict__ K,
                                                      const unsigned short* __restrict__ Vt,
                                                      const unsigned char* __restrict__ Mb,
                                                      unsigned short* __restrict__ Ctx) {
  __shared__ __align__(16) float Cmb[64 * 68];   // combine buffer, padded rows
  __shared__ float lpart[2][2][16];              // [qhalf][qg][l16], kh=1 partials

  const int tid  = threadIdx.x;
  const int wave = tid >> 6, lane = tid & 63;
  const int quad = lane >> 4, l16 = lane & 15;
  const int qhalf = wave >> 1, kh = wave & 1;
  const int qt = blockIdx.x, bh = blockIdx.y;
  const int b = bh / HN, h = bh - b * HN;

  const unsigned short* Qp = Q + (size_t)bh * SN * DKN;
  const unsigned short* Kp = K + (size_t)bh * SN * DKN;
  const unsigned short* Vp = Vt + (size_t)bh * DKN * SN;

  // direct fragment base addresses (kt-invariant parts hoisted)
  const int krow_base = kh * 32 + ((l16 >> 2) << 3) + (l16 & 3);
  const unsigned short* Kl = Kp + (size_t)krow_base * DKN + quad * 8;   // + kt*64*DKN (+ mt*4*DKN, +32)
  const unsigned short* Vl = Vp + (size_t)l16 * SN + kh * 32 + quad * 8; // + dt*16*SN + kt*64
  // keep-byte mask pointers (per qg): row*SN + kt*64 + kh*32 + quad*8, 8B-aligned
  const unsigned char* Ml0 =
      Mb + ((size_t)b * SN + (size_t)(qt * 64 + qhalf * 32 + l16)) * SN + kh * 32 + quad * 8;
  const unsigned char* Ml1 = Ml0 + (size_t)16 * SN;

  // Q B-fragments for this wave's 32 q-rows (2 groups of 16), hoisted
  bf16x8 bq[2][2];
#pragma unroll
  for (int qg = 0; qg < 2; ++qg) {
    const int R = qt * 64 + qhalf * 32 + qg * 16 + l16;
    bq[qg][0] = *(const bf16x8*)(Qp + (size_t)R * DKN + quad * 8);
    bq[qg][1] = *(const bf16x8*)(Qp + (size_t)R * DKN + 32 + quad * 8);
  }

  f32x4 o_acc[2][4] = {};
  f32x4 o_l[2] = {};
  bf16x8 ones;
#pragma unroll
  for (int i = 0; i < 8; ++i) ones[i] = (short)0x3F80;  // bf16 1.0

  // current-tile fragment registers (rotated in place)
  bf16x8 ak00, ak01, ak10, ak11, av0, av1, av2, av3;
  uint2 mb0, mb1;

#define LD_K(t) { const unsigned short* kp_ = Kl + (size_t)(t) * (64 * DKN);           \
    ak00 = *(const bf16x8*)(kp_);            ak01 = *(const bf16x8*)(kp_ + 32);        \
    ak10 = *(const bf16x8*)(kp_ + 4 * DKN);  ak11 = *(const bf16x8*)(kp_ + 4 * DKN + 32); }
#define LD_V(t) { const unsigned short* vp_ = Vl + (size_t)(t) * 64;                   \
    av0 = *(const bf16x8*)(vp_);                 av1 = *(const bf16x8*)(vp_ + 16 * SN); \
    av2 = *(const bf16x8*)(vp_ + 32 * SN);       av3 = *(const bf16x8*)(vp_ + 48 * SN); }
#define LD_M(t) { mb0 = *(const uint2*)(Ml0 + (size_t)(t) * 64);                       \
                  mb1 = *(const uint2*)(Ml1 + (size_t)(t) * 64); }

  LD_K(0); LD_V(0); LD_M(0);

  for (int kt = 0; kt < 32; ++kt) {
    const int ktn = (kt + 1) & 31;

    // ---- S^T = K x Q^T for 32q x 32k (both qg) — consumes ak
    f32x4 s[2][2];
#pragma unroll
    for (int qg = 0; qg < 2; ++qg) {
      f32x4 c0 = {}, c1 = {};
      c0 = __builtin_amdgcn_mfma_f32_16x16x32_bf16(ak00, bq[qg][0], c0, 0, 0, 0);
      c0 = __builtin_amdgcn_mfma_f32_16x16x32_bf16(ak01, bq[qg][1], c0, 0, 0, 0);
      c1 = __builtin_amdgcn_mfma_f32_16x16x32_bf16(ak10, bq[qg][0], c1, 0, 0, 0);
      c1 = __builtin_amdgcn_mfma_f32_16x16x32_bf16(ak11, bq[qg][1], c1, 0, 0, 0);
      s[qg][0] = c0; s[qg][1] = c1;
    }
    LD_K(ktn);   // prefetch next K — covered by softmax+PV+next-iter wait

    // ---- p = exp2(s) & keep-mask (byte table), PV + l via MFMA — consumes mb, av
#pragma unroll
    for (int qg = 0; qg < 2; ++qg) {
      const unsigned mx = qg ? mb1.x : mb0.x;
      const unsigned my = qg ? mb1.y : mb0.y;
      union { unsigned u[4]; bf16x8 v; } pk;
      pk.u[0] = pk_bf16(__builtin_exp2f(s[qg][0][0]), __builtin_exp2f(s[qg][0][1])) & pmexp(mx, 0x01010000u);
      pk.u[1] = pk_bf16(__builtin_exp2f(s[qg][0][2]), __builtin_exp2f(s[qg][0][3])) & pmexp(mx, 0x03030202u);
      pk.u[2] = pk_bf16(__builtin_exp2f(s[qg][1][0]), __builtin_exp2f(s[qg][1][1])) & pmexp(my, 0x01010000u);
      pk.u[3] = pk_bf16(__builtin_exp2f(s[qg][1][2]), __builtin_exp2f(s[qg][1][3])) & pmexp(my, 0x03030202u);
      o_l[qg] = __builtin_amdgcn_mfma_f32_16x16x32_bf16(ones, pk.v, o_l[qg], 0, 0, 0);
      o_acc[qg][0] = __builtin_amdgcn_mfma_f32_16x16x32_bf16(av0, pk.v, o_acc[qg][0], 0, 0, 0);
      o_acc[qg][1] = __builtin_amdgcn_mfma_f32_16x16x32_bf16(av1, pk.v, o_acc[qg][1], 0, 0, 0);
      o_acc[qg][2] = __builtin_amdgcn_mfma_f32_16x16x32_bf16(av2, pk.v, o_acc[qg][2], 0, 0, 0);
      o_acc[qg][3] = __builtin_amdgcn_mfma_f32_16x16x32_bf16(av3, pk.v, o_acc[qg][3], 0, 0, 0);
    }
    LD_M(ktn);   // prefetch next mask
    LD_V(ktn);   // prefetch next V
  }
#undef LD_K
#undef LD_V
#undef LD_M

  // combine the two key-halves (once)
  __syncthreads();
  if (kh == 1) {
#pragma unroll
    for (int qg = 0; qg < 2; ++qg) {
#pragma unroll
      for (int dt = 0; dt < 4; ++dt)
        *(f32x4*)&Cmb[(qhalf * 32 + qg * 16 + l16) * 68 + dt * 16 + quad * 4] = o_acc[qg][dt];
      if (quad == 0) lpart[qhalf][qg][l16] = o_l[qg][0];
    }
  }
  __syncthreads();
  if (kh == 0) {
#pragma unroll
    for (int qg = 0; qg < 2; ++qg) {
      const float l = o_l[qg][0] + lpart[qhalf][qg][l16];
      const float inv = 1.0f / l;
      const int R = qt * 64 + qhalf * 32 + qg * 16 + l16;
      unsigned short* Crow = Ctx + (size_t)(b * SN + R) * EN + h * 64;
#pragma unroll
      for (int dt = 0; dt < 4; ++dt) {
        const f32x4 part = *(const f32x4*)&Cmb[(qhalf * 32 + qg * 16 + l16) * 68 + dt * 16 + quad * 4];
        ushort4 wst;
        wst.x = f2bf((o_acc[qg][dt][0] + part[0]) * inv);
        wst.y = f2bf((o_acc[qg][dt][1] + part[1]) * inv);
        wst.z = f2bf((o_acc[qg][dt][2] + part[2]) * inv);
        wst.w = f2bf((o_acc[qg][dt][3] + part[3]) * inv);
        *(ushort4*)&Crow[dt * 16 + quad * 4] = wst;
      }
    }
  }
}

// ---------------------------------------------------------------- LayerNorm rows of 768
__global__ __launch_bounds__(256) void ln_kernel(const float* __restrict__ X,
                                                 float* __restrict__ Y) {
  const int row = blockIdx.x;
  const int t = threadIdx.x;
  const float* xr = X + (size_t)row * EN;
  float v[3];
  float s = 0.f, ss = 0.f;
#pragma unroll
  for (int i = 0; i < 3; ++i) {
    v[i] = xr[t + i * 256];
    s += v[i];
    ss += v[i] * v[i];
  }
#pragma unroll
  for (int off = 1; off < 64; off <<= 1) {
    s += __shfl_xor(s, off, 64);
    ss += __shfl_xor(ss, off, 64);
  }
  __shared__ float ws_s[4], ws_q[4];
  const int wave = t >> 6, lane = t & 63;
  if (lane == 0) { ws_s[wave] = s; ws_q[wave] = ss; }
  __syncthreads();
  s = ws_s[0] + ws_s[1] + ws_s[2] + ws_s[3];
  ss = ws_q[0] + ws_q[1] + ws_q[2] + ws_q[3];
  const float mean = s * (1.0f / EN);
  const float var = ss * (1.0f / EN) - mean * mean;
  const float rstd = rsqrtf(var + 1e-5f);
  float* yr = Y + (size_t)row * EN;
#pragma unroll
  for (int i = 0; i < 3; ++i) yr[t + i * 256] = (v[i] - mean) * rstd;
}

// ---------------------------------------------------------------- launch
extern "C" void kernel_launch(void* const* d_in, const int* in_sizes, int n_in,
                              void* d_out, int out_size, void* d_ws, size_t ws_size,
                              hipStream_t stream) {
  (void)in_sizes; (void)n_in; (void)out_size; (void)ws_size;
  const float* query = (const float*)d_in[0];
  const float* key_i = (const float*)d_in[1];
  const float* value = (const float*)d_in[2];
  const int*   mask  = (const int*)d_in[3];
  const float* Wq = (const float*)d_in[4];
  const float* Wk = (const float*)d_in[5];
  const float* Wv = (const float*)d_in[6];
  const float* Wo = (const float*)d_in[7];

  const size_t NBIG = (size_t)MROWS * EN;  // 6291456
  const size_t NW   = (size_t)EN * EN;     // 589824

  unsigned short* Xq16 = (unsigned short*)d_ws;   // X bank: q,k,v contiguous
  unsigned short* Wq16 = Xq16 + 3 * NBIG;         // W bank: wq,wk,wv,wo contiguous
  unsigned short* Wo16 = Wq16 + 3 * NW;
  unsigned short* Q16  = Wo16 + NW;               // out bank: Q,K,Vt contiguous
  unsigned short* K16  = Q16 + NBIG;
  unsigned short* Vt16 = K16 + NBIG;
  unsigned short* Ctx16 = Vt16 + NBIG;
  float* OutF = (float*)(Ctx16 + NBIG);
  // keep-byte mask table (16.8 MB) aliases OutF (25.2 MB): attn reads it BEFORE
  // gemm_out writes OutF (stream-ordered), same discipline as the old Mbits alias.
  unsigned char* Mbytes = (unsigned char*)OutF;

  // total keys = B*S*S = 16,777,216 ; 4 per thread -> 4,194,304 threads -> 16384 blocks
  mask_bytes<<<16384, 256, 0, stream>>>(mask, (unsigned*)Mbytes);

  const int ncvt = 3 * NBIG4 + 4 * NW4;
  cvt_all<<<ncvt / 256, 256, 0, stream>>>(query, key_i, value, Wq, Wk, Wv, Wo, Xq16);

  // Q scale: 1/sqrt(dk) * log2(e) so softmax is a bare exp2
  gemm_qkv<<<dim3(MROWS / 128, EN / 128, 3), 256, 0, stream>>>(
      Xq16, Wq16, Q16, 0.125f * 1.44269504088896f);

  attn_kernel<<<dim3(SN / 64, BATCH * HN), 256, 0, stream>>>(
      Q16, K16, Vt16, Mbytes, Ctx16);

  gemm_out<<<dim3(MROWS / 128, EN / 128), 256, 0, stream>>>(Ctx16, Wo16, OutF, query);

  ln_kernel<<<MROWS, 256, 0, stream>>>(OutF, (float*)d_out);
}

// Round 4
// 363.304 us; speedup vs baseline: 1.3714x; 1.3714x over previous
//
#include <hip/hip_runtime.h>
#include <stdint.h>
#include <stddef.h>

#define HN   12
#define SN   2048
#define EN   768
#define DKN  64
#define BATCH 4
#define MROWS 8192   // BATCH*SN

typedef short bf16x8 __attribute__((ext_vector_type(8)));
typedef float f32x4 __attribute__((ext_vector_type(4)));

__device__ __forceinline__ unsigned short f2bf(float f) {
  union { float f; unsigned u; } x; x.f = f;
  unsigned r = x.u + 0x7fffu + ((x.u >> 16) & 1u);
  return (unsigned short)(r >> 16);
}

#if __has_builtin(__builtin_amdgcn_cvt_pk_bf16_f32)
typedef __bf16 bf16v2 __attribute__((ext_vector_type(2)));
__device__ __forceinline__ unsigned pk_bf16(float a, float b) {
  union { bf16v2 v; unsigned u; } c;
  c.v = __builtin_amdgcn_cvt_pk_bf16_f32(a, b);
  return c.u;
}
#else
__device__ __forceinline__ unsigned pk_bf16(float a, float b) {
  return (unsigned)f2bf(a) | ((unsigned)f2bf(b) << 16);
}
#endif

// byte-pair expand via v_perm: sel 0x01010000 -> [b0 b0 b1 b1] (lo16=b0b0, hi16=b1b1),
// sel 0x03030202 -> [b2 b2 b3 b3]. Mask bytes are 0xFF (keep) / 0x00 (exclude).
#if __has_builtin(__builtin_amdgcn_perm)
__device__ __forceinline__ unsigned pmexp(unsigned m, unsigned sel) {
  return __builtin_amdgcn_perm(m, m, sel);
}
#else
__device__ __forceinline__ unsigned pmexp(unsigned m, unsigned sel) {
  const unsigned b0 = (m >> (8 * (sel & 3))) & 0xFFu;
  const unsigned b1 = (m >> (8 * ((sel >> 16) & 3))) & 0xFFu;
  return (b0 ? 0xFFFFu : 0u) | (b1 ? 0xFFFF0000u : 0u);
}
#endif

#define GLD_LDS16(gptr, lptr) \
  __builtin_amdgcn_global_load_lds((const __attribute__((address_space(1))) void*)(gptr), \
                                   (__attribute__((address_space(3))) void*)(lptr), 16, 0, 0)

// ---------------------------------------------------------------- fused f32 -> bf16
#define NBIG4 1572864   // NBIG/4
#define NW4   147456    // NW/4
__global__ __launch_bounds__(256) void cvt_all(const float* __restrict__ q,
                                               const float* __restrict__ k,
                                               const float* __restrict__ v,
                                               const float* __restrict__ wq,
                                               const float* __restrict__ wk,
                                               const float* __restrict__ wv,
                                               const float* __restrict__ wo,
                                               unsigned short* __restrict__ dst) {
  const int i = blockIdx.x * 256 + threadIdx.x;
  const float* src;
  int off;
  if (i < 3 * NBIG4) {
    const int r = i / NBIG4;
    src = (r == 0) ? q : (r == 1) ? k : v;
    off = i - r * NBIG4;
  } else {
    const int j = i - 3 * NBIG4;
    const int r = j / NW4;
    src = (r == 0) ? wq : (r == 1) ? wk : (r == 2) ? wv : wo;
    off = j - r * NW4;
  }
  float4 val = ((const float4*)src)[off];
  ushort4 o;
  o.x = f2bf(val.x); o.y = f2bf(val.y); o.z = f2bf(val.z); o.w = f2bf(val.w);
  ((ushort4*)dst)[i] = o;
}

// ---------------------------------------------------------------- mask -> keep-byte table
// keep = (mask==0) -> 0xFF ; exclude -> 0x00.  out u32 packs 4 consecutive keys.
__global__ __launch_bounds__(256) void mask_bytes(const int* __restrict__ mask,
                                                  unsigned* __restrict__ out) {
  const size_t i = (size_t)blockIdx.x * 256 + threadIdx.x;
  const int4 v = ((const int4*)mask)[i];
  unsigned o = (v.x ? 0u : 0xFFu) | (v.y ? 0u : 0xFF00u) |
               (v.z ? 0u : 0xFF0000u) | (v.w ? 0u : 0xFF000000u);
  out[i] = o;
}

// ---------------------------------------------------------------- batched QKV GEMM
// z=0: Q (scaled, [B,H,S,DK]); z=1: K ([B,H,S,DK]); z=2: V transposed ([B,H,DK,S])
__global__ __launch_bounds__(256) void gemm_qkv(const unsigned short* __restrict__ Xb,
                                                const unsigned short* __restrict__ Wb,
                                                unsigned short* __restrict__ Ob,
                                                float qscale) {
  __shared__ unsigned short As[128 * 32];
  __shared__ unsigned short Bs[128 * 32];
  const int tid  = threadIdx.x;
  const int wave = tid >> 6;
  const int lane = tid & 63;
  const int quad = lane >> 4;
  const int l16  = lane & 15;
  const int bm = blockIdx.x;
  const int bn = blockIdx.y;
  const int z  = blockIdx.z;
  const int wm = wave & 1;
  const int wn = wave >> 1;

  const unsigned short* X = Xb + (size_t)z * MROWS * EN;
  const unsigned short* W = Wb + (size_t)z * EN * EN;
  unsigned short* O = Ob + (size_t)z * MROWS * EN;

  f32x4 acc[4][4] = {};
  const int srow = lane >> 2;
  const int schk = lane & 3;

  for (int bk = 0; bk < 24; ++bk) {
    __syncthreads();
#pragma unroll
    for (int r = 0; r < 2; ++r) {
      const int rowblk = r * 64 + wave * 16;
      GLD_LDS16(X + (size_t)(bm * 128 + rowblk + srow) * EN + bk * 32 + schk * 8,
                As + rowblk * 32);
      GLD_LDS16(W + (size_t)(bn * 128 + rowblk + srow) * EN + bk * 32 + schk * 8,
                Bs + rowblk * 32);
    }
    __syncthreads();

    bf16x8 af[4], bfr[4];
#pragma unroll
    for (int mt = 0; mt < 4; ++mt)
      af[mt] = *(const bf16x8*)&As[(wm * 64 + mt * 16 + l16) * 32 + quad * 8];
#pragma unroll
    for (int nt = 0; nt < 4; ++nt)
      bfr[nt] = *(const bf16x8*)&Bs[(wn * 64 + nt * 16 + l16) * 32 + quad * 8];
#pragma unroll
    for (int mt = 0; mt < 4; ++mt)
#pragma unroll
      for (int nt = 0; nt < 4; ++nt)
        acc[mt][nt] = __builtin_amdgcn_mfma_f32_16x16x32_bf16(af[mt], bfr[nt], acc[mt][nt], 0, 0, 0);
  }

  const int m0 = bm * 128 + wm * 64;
  const int n0 = bn * 128 + wn * 64;
  const float scale = (z == 0) ? qscale : 1.0f;

  if (z < 2) {
#pragma unroll
    for (int mt = 0; mt < 4; ++mt) {
#pragma unroll
      for (int nt = 0; nt < 4; ++nt) {
        const int n = n0 + nt * 16 + l16;
        const int h = n >> 6, d = n & 63;
#pragma unroll
        for (int r = 0; r < 4; ++r) {
          const int m = m0 + mt * 16 + quad * 4 + r;
          const int b = m >> 11, s = m & 2047;
          O[((size_t)(b * HN + h) * SN + s) * DKN + d] = f2bf(acc[mt][nt][r] * scale);
        }
      }
    }
  } else {
#pragma unroll
    for (int mt = 0; mt < 4; ++mt) {
#pragma unroll
      for (int nt = 0; nt < 4; ++nt) {
        const int n = n0 + nt * 16 + l16;
        const int h = n >> 6, d = n & 63;
        const int m = m0 + mt * 16 + quad * 4;
        const int b = m >> 11, s = m & 2047;
        ushort4 pk;
        pk.x = f2bf(acc[mt][nt][0]);
        pk.y = f2bf(acc[mt][nt][1]);
        pk.z = f2bf(acc[mt][nt][2]);
        pk.w = f2bf(acc[mt][nt][3]);
        *(ushort4*)&O[((size_t)(b * HN + h) * DKN + d) * SN + s] = pk;
      }
    }
  }
}

// ---------------------------------------------------------------- GEMM  C = X @ W^T + residual (f32 out)
__global__ __launch_bounds__(256) void gemm_out(const unsigned short* __restrict__ X,
                                                const unsigned short* __restrict__ W,
                                                float* __restrict__ O,
                                                const float* __restrict__ residual) {
  __shared__ unsigned short As[128 * 32];
  __shared__ unsigned short Bs[128 * 32];
  const int tid  = threadIdx.x;
  const int wave = tid >> 6;
  const int lane = tid & 63;
  const int quad = lane >> 4;
  const int l16  = lane & 15;
  const int bm = blockIdx.x;
  const int bn = blockIdx.y;
  const int wm = wave & 1;
  const int wn = wave >> 1;

  f32x4 acc[4][4] = {};
  const int srow = lane >> 2;
  const int schk = lane & 3;

  for (int bk = 0; bk < 24; ++bk) {
    __syncthreads();
#pragma unroll
    for (int r = 0; r < 2; ++r) {
      const int rowblk = r * 64 + wave * 16;
      GLD_LDS16(X + (size_t)(bm * 128 + rowblk + srow) * EN + bk * 32 + schk * 8,
                As + rowblk * 32);
      GLD_LDS16(W + (size_t)(bn * 128 + rowblk + srow) * EN + bk * 32 + schk * 8,
                Bs + rowblk * 32);
    }
    __syncthreads();

    bf16x8 af[4], bfr[4];
#pragma unroll
    for (int mt = 0; mt < 4; ++mt)
      af[mt] = *(const bf16x8*)&As[(wm * 64 + mt * 16 + l16) * 32 + quad * 8];
#pragma unroll
    for (int nt = 0; nt < 4; ++nt)
      bfr[nt] = *(const bf16x8*)&Bs[(wn * 64 + nt * 16 + l16) * 32 + quad * 8];
#pragma unroll
    for (int mt = 0; mt < 4; ++mt)
#pragma unroll
      for (int nt = 0; nt < 4; ++nt)
        acc[mt][nt] = __builtin_amdgcn_mfma_f32_16x16x32_bf16(af[mt], bfr[nt], acc[mt][nt], 0, 0, 0);
  }

  const int m0 = bm * 128 + wm * 64;
  const int n0 = bn * 128 + wn * 64;
#pragma unroll
  for (int mt = 0; mt < 4; ++mt) {
#pragma unroll
    for (int nt = 0; nt < 4; ++nt) {
      const int n = n0 + nt * 16 + l16;
#pragma unroll
      for (int r = 0; r < 4; ++r) {
        const int m = m0 + mt * 16 + quad * 4 + r;
        const size_t idx = (size_t)m * EN + n;
        O[idx] = acc[mt][nt][r] + residual[idx];
      }
    }
  }
}

// ---------------------------------------------------------------- flash attention (key-split waves)
// ROUND 4 = round-0 staged structure EXACTLY (proven 123.4 us), with ONE change:
// mask application moved from pre-exp2 shift/select (2-3 VALU/score) to post-exp2
// byte-table AND (4 v_perm + 4 v_and per qg). Mask bytes (0xFF keep / 0x00 excl)
// loaded as 2x 8B inside the staging window (free cover under gld_lds drain).
// Wave = (qhalf, keyhalf): 32q x 32k. O additive over keys -> combine halves at end.
// Q pre-scaled by 0.125*log2e (bare exp2 softmax, uniform bias cancels in O/l).
__global__ __launch_bounds__(256, 4) void attn_kernel(const unsigned short* __restrict__ Q,
                                                      const unsigned short* __restrict__ K,
                                                      const unsigned short* __restrict__ Vt,
                                                      const unsigned char* __restrict__ Mb,
                                                      unsigned short* __restrict__ Ctx) {
  __shared__ __align__(16) unsigned char LDSBUF[64 * 68 * 4];  // staging (16KB) / combine (17408B)
  __shared__ float lpart[2][2][16];                            // [qhalf][qg][l16], kh=1 partials
  unsigned short* Ks = (unsigned short*)LDSBUF;                // [64][64] perm-key x d
  unsigned short* Vs = (unsigned short*)(LDSBUF + 8192);       // [64][64] d x key
  float* Cmb = (float*)LDSBUF;                                 // [64][68] q x d, padded

  const int tid  = threadIdx.x;
  const int wave = tid >> 6, lane = tid & 63;
  const int quad = lane >> 4, l16 = lane & 15;
  const int qhalf = wave >> 1, kh = wave & 1;
  const int qt = blockIdx.x, bh = blockIdx.y;
  const int b = bh / HN, h = bh - b * HN;

  const unsigned short* Qp = Q + (size_t)bh * SN * DKN;
  const unsigned short* Kp = K + (size_t)bh * SN * DKN;
  const unsigned short* Vp = Vt + (size_t)bh * DKN * SN;

  const int srow = lane >> 3;
  const int schk = lane & 7;
  const int swsrc = (schk ^ srow) * 8;
  const int c0 = (quad ^ (l16 & 7)) * 8;                    // K frag chunks (d)
  const int cv = (((kh << 2) + quad) ^ (l16 & 7)) * 8;      // V frag chunk (key half kh)

  // K staging: dest physical row (within half) pw holds logical key yk
  const int pw = wave * 8 + srow;
  const int yk = (((pw >> 2) & 3) << 3) + ((pw >> 4) << 2) + (pw & 3);

  // Q B-fragments for this wave's 32 q-rows (2 groups of 16), hoisted
  bf16x8 bq[2][2];
#pragma unroll
  for (int qg = 0; qg < 2; ++qg) {
    const int R = qt * 64 + qhalf * 32 + qg * 16 + l16;
    bq[qg][0] = *(const bf16x8*)(Qp + (size_t)R * DKN + quad * 8);
    bq[qg][1] = *(const bf16x8*)(Qp + (size_t)R * DKN + 32 + quad * 8);
  }

  // keep-byte mask pointers: row*SN + kt*64 + kh*32 + quad*8 (8B-aligned); qg=1 at +16 rows
  const unsigned char* Ml0 =
      Mb + ((size_t)b * SN + (size_t)(qt * 64 + qhalf * 32 + l16)) * SN + kh * 32 + quad * 8;
  const unsigned char* Ml1 = Ml0 + (size_t)16 * SN;

  f32x4 o_acc[2][4] = {};
  f32x4 o_l[2] = {};
  bf16x8 ones;
#pragma unroll
  for (int i = 0; i < 8; ++i) ones[i] = (short)0x3F80;  // bf16 1.0

  for (int kt = 0; kt < 32; ++kt) {
    __syncthreads();
    GLD_LDS16(Kp + (size_t)(kt * 64 + yk) * DKN + swsrc,              Ks + (wave * 8) * 64);
    GLD_LDS16(Kp + (size_t)(kt * 64 + 32 + yk) * DKN + swsrc,         Ks + (32 + wave * 8) * 64);
    GLD_LDS16(Vp + (size_t)(wave * 8 + srow) * SN + kt * 64 + swsrc,      Vs + (wave * 8) * 64);
    GLD_LDS16(Vp + (size_t)(32 + wave * 8 + srow) * SN + kt * 64 + swsrc, Vs + (32 + wave * 8) * 64);
    const uint2 mbv0 = *(const uint2*)(Ml0 + (size_t)kt * 64);
    const uint2 mbv1 = *(const uint2*)(Ml1 + (size_t)kt * 64);
    __syncthreads();

    // K fragments: this wave's key-half only
    bf16x8 ak[2][2];
#pragma unroll
    for (int mt = 0; mt < 2; ++mt) {
      const int base = (kh * 32 + mt * 16 + l16) * 64;
      ak[mt][0] = *(const bf16x8*)&Ks[base + c0];
      ak[mt][1] = *(const bf16x8*)&Ks[base + (c0 ^ 32)];
    }

    // S^T = K x Q^T for 32q x 32k
    f32x4 st[2][2];
#pragma unroll
    for (int qg = 0; qg < 2; ++qg)
#pragma unroll
      for (int mt = 0; mt < 2; ++mt) {
        f32x4 c = {};
        c = __builtin_amdgcn_mfma_f32_16x16x32_bf16(ak[mt][0], bq[qg][0], c, 0, 0, 0);
        c = __builtin_amdgcn_mfma_f32_16x16x32_bf16(ak[mt][1], bq[qg][1], c, 0, 0, 0);
        st[qg][mt] = c;
      }

    // V fragments (shared across qg): key chunk for half kh
    bf16x8 av[4];
#pragma unroll
    for (int dt = 0; dt < 4; ++dt)
      av[dt] = *(const bf16x8*)&Vs[(dt * 16 + l16) * 64 + cv];

    // p = exp2(s), then AND with expanded keep-bytes (k = quad*8 + mt*4 + r)
#pragma unroll
    for (int qg = 0; qg < 2; ++qg) {
      const unsigned mx = qg ? mbv1.x : mbv0.x;   // bytes for mt=0 (r=0..3)
      const unsigned my = qg ? mbv1.y : mbv0.y;   // bytes for mt=1 (r=0..3)
      union { unsigned u[4]; bf16x8 v; } pk;
      pk.u[0] = pk_bf16(__builtin_exp2f(st[qg][0][0]), __builtin_exp2f(st[qg][0][1])) & pmexp(mx, 0x01010000u);
      pk.u[1] = pk_bf16(__builtin_exp2f(st[qg][0][2]), __builtin_exp2f(st[qg][0][3])) & pmexp(mx, 0x03030202u);
      pk.u[2] = pk_bf16(__builtin_exp2f(st[qg][1][0]), __builtin_exp2f(st[qg][1][1])) & pmexp(my, 0x01010000u);
      pk.u[3] = pk_bf16(__builtin_exp2f(st[qg][1][2]), __builtin_exp2f(st[qg][1][3])) & pmexp(my, 0x03030202u);
      o_l[qg] = __builtin_amdgcn_mfma_f32_16x16x32_bf16(ones, pk.v, o_l[qg], 0, 0, 0);
#pragma unroll
      for (int dt = 0; dt < 4; ++dt)
        o_acc[qg][dt] = __builtin_amdgcn_mfma_f32_16x16x32_bf16(av[dt], pk.v, o_acc[qg][dt], 0, 0, 0);
    }
  }

  // combine the two key-halves (once)
  __syncthreads();
  if (kh == 1) {
#pragma unroll
    for (int qg = 0; qg < 2; ++qg) {
#pragma unroll
      for (int dt = 0; dt < 4; ++dt)
        *(f32x4*)&Cmb[(qhalf * 32 + qg * 16 + l16) * 68 + dt * 16 + quad * 4] = o_acc[qg][dt];
      if (quad == 0) lpart[qhalf][qg][l16] = o_l[qg][0];
    }
  }
  __syncthreads();
  if (kh == 0) {
#pragma unroll
    for (int qg = 0; qg < 2; ++qg) {
      const float l = o_l[qg][0] + lpart[qhalf][qg][l16];
      const float inv = 1.0f / l;
      const int R = qt * 64 + qhalf * 32 + qg * 16 + l16;
      unsigned short* Crow = Ctx + (size_t)(b * SN + R) * EN + h * 64;
#pragma unroll
      for (int dt = 0; dt < 4; ++dt) {
        const f32x4 part = *(const f32x4*)&Cmb[(qhalf * 32 + qg * 16 + l16) * 68 + dt * 16 + quad * 4];
        ushort4 wst;
        wst.x = f2bf((o_acc[qg][dt][0] + part[0]) * inv);
        wst.y = f2bf((o_acc[qg][dt][1] + part[1]) * inv);
        wst.z = f2bf((o_acc[qg][dt][2] + part[2]) * inv);
        wst.w = f2bf((o_acc[qg][dt][3] + part[3]) * inv);
        *(ushort4*)&Crow[dt * 16 + quad * 4] = wst;
      }
    }
  }
}

// ---------------------------------------------------------------- LayerNorm rows of 768
__global__ __launch_bounds__(256) void ln_kernel(const float* __restrict__ X,
                                                 float* __restrict__ Y) {
  const int row = blockIdx.x;
  const int t = threadIdx.x;
  const float* xr = X + (size_t)row * EN;
  float v[3];
  float s = 0.f, ss = 0.f;
#pragma unroll
  for (int i = 0; i < 3; ++i) {
    v[i] = xr[t + i * 256];
    s += v[i];
    ss += v[i] * v[i];
  }
#pragma unroll
  for (int off = 1; off < 64; off <<= 1) {
    s += __shfl_xor(s, off, 64);
    ss += __shfl_xor(ss, off, 64);
  }
  __shared__ float ws_s[4], ws_q[4];
  const int wave = t >> 6, lane = t & 63;
  if (lane == 0) { ws_s[wave] = s; ws_q[wave] = ss; }
  __syncthreads();
  s = ws_s[0] + ws_s[1] + ws_s[2] + ws_s[3];
  ss = ws_q[0] + ws_q[1] + ws_q[2] + ws_q[3];
  const float mean = s * (1.0f / EN);
  const float var = ss * (1.0f / EN) - mean * mean;
  const float rstd = rsqrtf(var + 1e-5f);
  float* yr = Y + (size_t)row * EN;
#pragma unroll
  for (int i = 0; i < 3; ++i) yr[t + i * 256] = (v[i] - mean) * rstd;
}

// ---------------------------------------------------------------- launch
extern "C" void kernel_launch(void* const* d_in, const int* in_sizes, int n_in,
                              void* d_out, int out_size, void* d_ws, size_t ws_size,
                              hipStream_t stream) {
  (void)in_sizes; (void)n_in; (void)out_size; (void)ws_size;
  const float* query = (const float*)d_in[0];
  const float* key_i = (const float*)d_in[1];
  const float* value = (const float*)d_in[2];
  const int*   mask  = (const int*)d_in[3];
  const float* Wq = (const float*)d_in[4];
  const float* Wk = (const float*)d_in[5];
  const float* Wv = (const float*)d_in[6];
  const float* Wo = (const float*)d_in[7];

  const size_t NBIG = (size_t)MROWS * EN;  // 6291456
  const size_t NW   = (size_t)EN * EN;     // 589824

  unsigned short* Xq16 = (unsigned short*)d_ws;   // X bank: q,k,v contiguous
  unsigned short* Wq16 = Xq16 + 3 * NBIG;         // W bank: wq,wk,wv,wo contiguous
  unsigned short* Wo16 = Wq16 + 3 * NW;
  unsigned short* Q16  = Wo16 + NW;               // out bank: Q,K,Vt contiguous
  unsigned short* K16  = Q16 + NBIG;
  unsigned short* Vt16 = K16 + NBIG;
  unsigned short* Ctx16 = Vt16 + NBIG;
  float* OutF = (float*)(Ctx16 + NBIG);
  // keep-byte mask table (16.8 MB) aliases OutF (25.2 MB): attn reads it BEFORE
  // gemm_out writes OutF (stream-ordered), same discipline as the old Mbits alias.
  unsigned char* Mbytes = (unsigned char*)OutF;

  // total keys = B*S*S = 16,777,216 ; 4 per thread -> 16384 blocks
  mask_bytes<<<16384, 256, 0, stream>>>(mask, (unsigned*)Mbytes);

  const int ncvt = 3 * NBIG4 + 4 * NW4;
  cvt_all<<<ncvt / 256, 256, 0, stream>>>(query, key_i, value, Wq, Wk, Wv, Wo, Xq16);

  // Q scale: 1/sqrt(dk) * log2(e) so softmax is a bare exp2
  gemm_qkv<<<dim3(MROWS / 128, EN / 128, 3), 256, 0, stream>>>(
      Xq16, Wq16, Q16, 0.125f * 1.44269504088896f);

  attn_kernel<<<dim3(SN / 64, BATCH * HN), 256, 0, stream>>>(
      Q16, K16, Vt16, Mbytes, Ctx16);

  gemm_out<<<dim3(MROWS / 128, EN / 128), 256, 0, stream>>>(Ctx16, Wo16, OutF, query);

  ln_kernel<<<MROWS, 256, 0, stream>>>(OutF, (float*)d_out);
}